// Round 5
// baseline (106.102 us; speedup 1.0000x reference)
//
#include <hip/hip_runtime.h>
#include <math.h>

// ---------------------------------------------------------------------------
// EEGGENET fused implementation (round 5).
// Shapes: B=64, C=64, T=1000, F1=8, D=2, F2=16, KLEN=64, NCLS=4.
//
// Algebra: graph conv + spatial conv + BN1 + BN2 fold into Wf[48][64]; channel
// contraction commutes with the temporal conv:
//   s[b,oc,t] = sum_q tw[f(oc),q] * p[oc][t-32+q] + bias[oc],
//   p[oc][u]  = sum_j Wf[oc][j] x[b,j,u]
// Stage1: 512 blocks (b x 8 tiles of 16 pool-outputs), 4 waves/block.
//   Wave w owns ocs 12w..12w+11. Lane = col-quad (float4), 256-col window.
//   Weights via wave-uniform scalar loads (SGPR broadcast); x via 4-deep
//   static software pipeline; ps wave-private in LDS (no mix->FIR barrier).
// ---------------------------------------------------------------------------

#define EPS_BN 1e-3f

// ws layout (floats)
#define WF_OFF   0        // WfT[64][48]  (j-major, BN1*BN2 folded)
#define BIAS_OFF 3072     // bias[48]
#define A3_OFF   3120     // a3[16]
#define C3_OFF   3136     // c3[16]
#define CLS_OFF  3152     // renormed cls_w [4][240]
#define OUT1_OFF 4176     // pooled stage-1 output [64][48][125]

// ---------------------------------------------------------------------------
__global__ __launch_bounds__(256) void eeg_setup_kernel(
    const float* __restrict__ g1, const float* __restrict__ b1,
    const float* __restrict__ m1, const float* __restrict__ v1,
    const float* __restrict__ e1, const float* __restrict__ e2,
    const float* __restrict__ sw,
    const float* __restrict__ g2, const float* __restrict__ b2,
    const float* __restrict__ m2, const float* __restrict__ v2,
    const float* __restrict__ g3, const float* __restrict__ b3,
    const float* __restrict__ m3, const float* __restrict__ v3,
    const float* __restrict__ clsw, float* __restrict__ ws)
{
    const int tid = threadIdx.x;
    const int blk = blockIdx.x;

    if (blk < 48) {
        const int oc = blk;
        const int k = oc >> 4;          // hop: 0=identity, 1=A1, 2=A2
        __shared__ float A[64][65];
        __shared__ float rsl[64];
        __shared__ float swl[64];
        __shared__ float sred;

        if (k > 0) {
            const float* e = (k == 1) ? e1 : e2;
            for (int idx = tid; idx < 4096; idx += 256) {
                int i = idx >> 6, j = idx & 63;
                float v;
                if (i == j) v = 1.f;
                else {
                    int ii = i > j ? i : j, jj = i > j ? j : i;
                    v = e[ii * (ii - 1) / 2 + jj];
                }
                A[i][j] = v;
            }
        }
        if (tid < 64) swl[tid] = sw[oc * 64 + tid];
        __syncthreads();
        if (tid < 64) {
            if (k > 0) {
                float s = 0.f;
                for (int j = 0; j < 64; ++j) s += A[tid][j];
                rsl[tid] = 1.f / s;
            }
            float nv = swl[tid] * swl[tid];
            for (int off = 32; off; off >>= 1) nv += __shfl_down(nv, off);
            if (tid == 0) sred = nv;
        }
        __syncthreads();
        if (tid < 64) {
            const int j = tid;
            const float sn = fminf(1.f, 1.f / fmaxf(sqrtf(sred), 1e-7f));
            float w;
            if (k == 0) w = swl[j];
            else {
                float acc = 0.f;
                for (int c = 0; c < 64; ++c) acc += swl[c] * rsl[c] * A[c][j];
                w = acc;
            }
            w *= sn;
            const int f = (oc >> 1) & 7;
            const float a1 = g1[f] * rsqrtf(v1[f] + EPS_BN);
            const float a2 = g2[oc] * rsqrtf(v2[oc] + EPS_BN);
            ws[WF_OFF + j * 48 + oc] = a2 * a1 * w;
            float S = w;
            for (int off = 32; off; off >>= 1) S += __shfl_down(S, off);
            if (tid == 0) {
                const float c1 = b1[f] - m1[f] * a1;
                const float c2 = b2[oc] - m2[oc] * a2;
                ws[BIAS_OFF + oc] = a2 * c1 * S + c2;
            }
        }
    } else {
        __shared__ float csc[4];
        if (tid < 16) {
            const float a3 = g3[tid] * rsqrtf(v3[tid] + EPS_BN);
            ws[A3_OFF + tid] = a3;
            ws[C3_OFF + tid] = b3[tid] - m3[tid] * a3;
        }
        {   // classifier renorm (maxnorm 0.25): row = wave
            const int row = tid >> 6, lane = tid & 63;
            float p = 0.f;
            if (row < 4)
                for (int idx = lane; idx < 240; idx += 64) {
                    float w = clsw[row * 240 + idx];
                    p += w * w;
                }
            for (int off = 32; off; off >>= 1) p += __shfl_down(p, off);
            if (row < 4 && lane == 0)
                csc[row] = fminf(1.f, 0.25f / fmaxf(sqrtf(p), 1e-7f));
        }
        __syncthreads();
        for (int idx = tid; idx < 960; idx += 256)
            ws[CLS_OFF + idx] = clsw[idx] * csc[idx / 240];
    }
}

// ---------------------------------------------------------------------------
struct W12 { float4 a, b, c; };

__device__ __forceinline__ W12 wload(const float* __restrict__ Wg, int j) {
    W12 w;
    const int jc = (j < 64) ? j : 63;          // clamp tail prefetch
    const float* p = Wg + jc * 48;
    w.a = *(const float4*)(p);
    w.b = *(const float4*)(p + 4);
    w.c = *(const float4*)(p + 8);
    return w;
}

__device__ __forceinline__ void fma12(float4* acc, const W12& w, const float4& xv) {
    const float wsv[12] = {w.a.x, w.a.y, w.a.z, w.a.w,
                           w.b.x, w.b.y, w.b.z, w.b.w,
                           w.c.x, w.c.y, w.c.z, w.c.w};
#pragma unroll
    for (int c = 0; c < 12; ++c) {
        acc[c].x += wsv[c] * xv.x;
        acc[c].y += wsv[c] * xv.y;
        acc[c].z += wsv[c] * xv.z;
        acc[c].w += wsv[c] * xv.w;
    }
}

// Stage 1: 512 blocks = (b, tile of 16 pool outputs). 39.9 KB LDS.
__global__ __launch_bounds__(256, 4) void eeg_stage1_kernel(
    const float* __restrict__ x, const float* __restrict__ tw,
    const float* __restrict__ wcon, float* __restrict__ out1)
{
    __shared__ float ps[4][12 * 196];   // wave-private [12][196]
    __shared__ float twl[512];
    __shared__ float biasl[48];
    const int tid = threadIdx.x;
    const int lane = tid & 63;
    const int wv = __builtin_amdgcn_readfirstlane(tid >> 6);  // wave id 0..3

    // XCD-aware swizzle (512 % 8 == 0, bijective): XCD k gets b = 8k..8k+7
    const int newid = (blockIdx.x & 7) * 64 + (blockIdx.x >> 3);
    const int b = newid >> 3;
    const int tile = newid & 7;
    const int o0 = tile * 16;
    const int no = (125 - o0) < 16 ? (125 - o0) : 16;   // 16, last tile 13
    const int u0 = 8 * o0 - 32;

    if (tid < 128) ((float4*)twl)[tid] = ((const float4*)tw)[tid];
    if (tid < 48) biasl[tid] = wcon[BIAS_OFF + tid];
    __syncthreads();

    // ---- channel mix: lane = col-quad, wave owns 12 ocs ----
    const float* Wg = wcon + WF_OFF + wv * 12;   // wave-uniform -> s_load
    const int u = u0 + 4 * lane;
    const bool valid = (u >= 0) && (u < 1000);   // quads never straddle
    const float* xq = x + (size_t)b * 64000 + (valid ? u : 0);
    const float4 fz = make_float4(0.f, 0.f, 0.f, 0.f);
#define LXJ(jj) (valid ? *(const float4*)(xq + (((jj) < 64) ? (jj) : 0) * 1000) : fz)

    float4 acc[12];
#pragma unroll
    for (int c = 0; c < 12; ++c) acc[c] = fz;

    float4 xp0 = LXJ(0), xp1 = LXJ(1), xp2 = LXJ(2), xp3 = LXJ(3);
    W12 wA = wload(Wg, 0), wB = wload(Wg, 1), wC = wload(Wg, 2), wD = wload(Wg, 3);

    for (int j0 = 0; j0 < 64; j0 += 4) {
        fma12(acc, wA, xp0);  xp0 = LXJ(j0 + 4);  wA = wload(Wg, j0 + 4);
        fma12(acc, wB, xp1);  xp1 = LXJ(j0 + 5);  wB = wload(Wg, j0 + 5);
        fma12(acc, wC, xp2);  xp2 = LXJ(j0 + 6);  wC = wload(Wg, j0 + 6);
        fma12(acc, wD, xp3);  xp3 = LXJ(j0 + 7);  wD = wload(Wg, j0 + 7);
    }
#undef LXJ

    float* psw = ps[wv];
    if (lane < 48) {            // cols 0..191 (window needs 191)
#pragma unroll
        for (int c = 0; c < 12; ++c)
            *(float4*)(&psw[c * 196 + 4 * lane]) = acc[c];
    }
    // ps is wave-private: same-wave ds_write -> ds_read, no barrier needed.

    // ---- FIR(64) + bias + ELU + pool8 (wave-local) ----
    const int ntasks = 12 * no;
    for (int p = 0; p < 3; ++p) {
        const int task = p * 64 + lane;
        if (task >= ntasks) break;
        const int oc = task % 12;         // oc-fastest: low LDS conflicts
        const int o = task / 12;
        const int ocg = wv * 12 + oc;
        const int f = (ocg >> 1) & 7;
        const float* row = psw + oc * 196 + o * 8;
        const float bs = biasl[ocg];
        float accv[8];
#pragma unroll
        for (int r = 0; r < 8; ++r) accv[r] = bs;
#pragma unroll
        for (int q0 = 0; q0 < 64; q0 += 8) {
            float win[16];
            const float4* pv = (const float4*)(row + q0);
#pragma unroll
            for (int gg = 0; gg < 4; ++gg) {
                float4 v = pv[gg];
                win[4 * gg + 0] = v.x; win[4 * gg + 1] = v.y;
                win[4 * gg + 2] = v.z; win[4 * gg + 3] = v.w;
            }
#pragma unroll
            for (int q = 0; q < 8; ++q) {
                float tv = twl[f * 64 + q0 + q];
#pragma unroll
                for (int r = 0; r < 8; ++r) accv[r] += tv * win[q + r];
            }
        }
        float s = 0.f;
#pragma unroll
        for (int r = 0; r < 8; ++r) {
            float v = accv[r];
            s += (v > 0.f) ? v : expm1f(v);
        }
        out1[((size_t)b * 48 + ocg) * 125 + (o0 + o)] = s * 0.125f;
    }
}

// ---------------------------------------------------------------------------
// Stage 2: per batch. dw conv(16,pad8) -> pw 48->16 -> BN3+ELU -> pool8 ->
// classifier. 64 blocks, float4 LDS staging.
// ---------------------------------------------------------------------------
#define SB_P1   0        // [48][125]  (reused for QQ [16][126])
#define SB_DWO  6000     // [48][126]  (reused for pooled [16][15])
#define SB_DWL  12048    // [48][16]
#define SB_PWL  12816    // [16][48]
#define SB_CLS  13584    // [4][240]
#define SB_A3   14544    // [16]
#define SB_C3   14560    // [16]
#define SB_TOT  14576

__global__ __launch_bounds__(256) void eeg_stage2_kernel(
    const float* __restrict__ ws, const float* __restrict__ dww,
    const float* __restrict__ pww, const float* __restrict__ clsb,
    float* __restrict__ out)
{
    __shared__ float sb[SB_TOT];
    const int tid = threadIdx.x;
    const int b = blockIdx.x;
    const float* o1 = ws + OUT1_OFF + (size_t)b * 6000;

    for (int i = tid; i < 1500; i += 256)
        ((float4*)(sb + SB_P1))[i] = ((const float4*)o1)[i];
    for (int i = tid; i < 192; i += 256)
        ((float4*)(sb + SB_DWL))[i] = ((const float4*)dww)[i];
    for (int i = tid; i < 192; i += 256)
        ((float4*)(sb + SB_PWL))[i] = ((const float4*)pww)[i];
    for (int i = tid; i < 240; i += 256)
        ((float4*)(sb + SB_CLS))[i] = ((const float4*)(ws + CLS_OFF))[i];
    if (tid < 16) { sb[SB_A3 + tid] = ws[A3_OFF + tid]; sb[SB_C3 + tid] = ws[C3_OFF + tid]; }
    __syncthreads();

    // depthwise conv: K=16, pad 8, T 125 -> 126
    for (int idx = tid; idx < 48 * 126; idx += 256) {
        int ci = idx / 126, t = idx - ci * 126;
        float acc = 0.f;
#pragma unroll
        for (int r = 0; r < 16; ++r) {
            int tt = t - 8 + r;
            float xv = (tt >= 0 && tt < 125) ? sb[SB_P1 + ci * 125 + tt] : 0.f;
            acc += sb[SB_DWL + ci * 16 + r] * xv;
        }
        sb[SB_DWO + idx] = acc;
    }
    __syncthreads();
    // pointwise 48->16 + BN3 + ELU  (overwrites P1 region, disjoint from DWO)
    for (int idx = tid; idx < 16 * 126; idx += 256) {
        int co = idx / 126, t = idx - co * 126;
        float acc = 0.f;
#pragma unroll
        for (int ci = 0; ci < 48; ++ci)
            acc += sb[SB_PWL + co * 48 + ci] * sb[SB_DWO + ci * 126 + t];
        float v = sb[SB_A3 + co] * acc + sb[SB_C3 + co];
        sb[SB_P1 + idx] = (v > 0.f) ? v : expm1f(v);
    }
    __syncthreads();
    // pool8: 126 -> 15 (overwrites DWO region)
    for (int idx = tid; idx < 240; idx += 256) {
        int co = idx / 15, v = idx - co * 15;
        float s = 0.f;
#pragma unroll
        for (int r = 0; r < 8; ++r) s += sb[SB_P1 + co * 126 + v * 8 + r];
        sb[SB_DWO + idx] = s * 0.125f;
    }
    __syncthreads();
    // classifier: wave w -> class w, 64-lane reduce over 240
    {
        const int wv = tid >> 6, lane = tid & 63;
        float p = 0.f;
        for (int j2 = lane; j2 < 240; j2 += 64)
            p += sb[SB_CLS + wv * 240 + j2] * sb[SB_DWO + j2];
        for (int off = 32; off; off >>= 1) p += __shfl_down(p, off);
        if (lane == 0) out[(size_t)b * 4 + wv] = p + clsb[wv];
    }
}

extern "C" void kernel_launch(void* const* d_in, const int* in_sizes, int n_in,
                              void* d_out, int out_size, void* d_ws, size_t ws_size,
                              hipStream_t stream) {
    const float* x    = (const float*)d_in[0];
    const float* tw   = (const float*)d_in[1];
    const float* g1   = (const float*)d_in[2];
    const float* b1   = (const float*)d_in[3];
    const float* m1   = (const float*)d_in[4];
    const float* v1   = (const float*)d_in[5];
    const float* e1   = (const float*)d_in[6];
    const float* e2   = (const float*)d_in[7];
    const float* sw   = (const float*)d_in[8];
    const float* g2   = (const float*)d_in[9];
    const float* b2   = (const float*)d_in[10];
    const float* m2   = (const float*)d_in[11];
    const float* v2   = (const float*)d_in[12];
    const float* dww  = (const float*)d_in[13];
    const float* pww  = (const float*)d_in[14];
    const float* g3   = (const float*)d_in[15];
    const float* b3   = (const float*)d_in[16];
    const float* m3   = (const float*)d_in[17];
    const float* v3   = (const float*)d_in[18];
    const float* clsw = (const float*)d_in[19];
    const float* clsb = (const float*)d_in[20];
    float* ws = (float*)d_ws;
    float* out = (float*)d_out;

    eeg_setup_kernel<<<49, 256, 0, stream>>>(g1, b1, m1, v1, e1, e2, sw,
                                             g2, b2, m2, v2, g3, b3, m3, v3,
                                             clsw, ws);
    eeg_stage1_kernel<<<512, 256, 0, stream>>>(x, tw, ws, ws + OUT1_OFF);
    eeg_stage2_kernel<<<64, 256, 0, stream>>>(ws, dww, pww, clsb, out);
}